// Round 1
// baseline (347.554 us; speedup 1.0000x reference)
//
#include <hip/hip_runtime.h>

// ---------------------------------------------------------------------------
// GCN 3-layer forward. fp32 throughout (no fp32 MFMA on CDNA4 -> vector GEMM).
// CSR-by-dst built once per launch, reused by all 3 aggregation passes.
// ---------------------------------------------------------------------------

__global__ void k_init(int* __restrict__ deg, int* __restrict__ cursor, int n) {
    int i = blockIdx.x * blockDim.x + threadIdx.x;
    if (i < n) { deg[i] = 1; cursor[i] = 0; }   // deg starts at 1 (self-loop)
}

__global__ void k_hist(const int* __restrict__ dst, int E, int* __restrict__ deg) {
    int e = blockIdx.x * blockDim.x + threadIdx.x;
    if (e < E) atomicAdd(&deg[dst[e]], 1);
}

// per-block exclusive scan (256 elems) + block sums; also dinv = deg^-0.5
__global__ void k_scan_block(const int* __restrict__ deg, int* __restrict__ offs,
                             int* __restrict__ bsum, float* __restrict__ dinv, int n) {
    __shared__ int sm[256];
    int tid = threadIdx.x;
    int i = blockIdx.x * 256 + tid;
    int v = (i < n) ? deg[i] : 0;
    if (i < n) dinv[i] = rsqrtf((float)v);
    sm[tid] = v;
    __syncthreads();
    for (int off = 1; off < 256; off <<= 1) {
        int t = (tid >= off) ? sm[tid - off] : 0;
        __syncthreads();
        sm[tid] += t;
        __syncthreads();
    }
    if (i < n) offs[i] = sm[tid] - v;            // exclusive within block
    if (tid == 255) bsum[blockIdx.x] = sm[255];  // block total
}

// single-block exclusive scan of block sums (nb <= 256)
__global__ void k_scan_bsum(int* __restrict__ bsum, int nb) {
    __shared__ int sm[256];
    int tid = threadIdx.x;
    int v = (tid < nb) ? bsum[tid] : 0;
    sm[tid] = v;
    __syncthreads();
    for (int off = 1; off < 256; off <<= 1) {
        int t = (tid >= off) ? sm[tid - off] : 0;
        __syncthreads();
        sm[tid] += t;
        __syncthreads();
    }
    if (tid < nb) bsum[tid] = sm[tid] - v;       // exclusive
}

__global__ void k_add_bsum(int* __restrict__ offs, const int* __restrict__ bsum,
                           int n, int total) {
    int i = blockIdx.x * blockDim.x + threadIdx.x;
    if (i < n) offs[i] += bsum[i >> 8];
    if (i == 0) offs[n] = total;
}

// scatter edges into CSR slots; norm precomputed once (same for all 3 layers)
__global__ void k_fill(const int* __restrict__ src, const int* __restrict__ dst,
                       int E, int n,
                       const int* __restrict__ offs, int* __restrict__ cursor,
                       const float* __restrict__ dinv,
                       int* __restrict__ esrc, float* __restrict__ enorm) {
    int e = blockIdx.x * blockDim.x + threadIdx.x;
    int tot = E + n;
    if (e >= tot) return;
    int s = (e < E) ? src[e] : (e - E);
    int d = (e < E) ? dst[e] : (e - E);
    int pos = offs[d] + atomicAdd(&cursor[d], 1);
    esrc[pos] = s;
    enorm[pos] = dinv[s] * dinv[d];
}

// ---------------------------------------------------------------------------
// fp32 tiled GEMM: C[n][OUT] = X[n][128] @ W[128][OUT].
// BM=64, BN=64, thread tile 4x4, K staged in 2 chunks of 64 (LDS 2*17KB, pad 68).
// ---------------------------------------------------------------------------
template <int OUT>
__global__ __launch_bounds__(256) void k_gemm(const float* __restrict__ X,
                                              const float* __restrict__ W,
                                              float* __restrict__ C, int n) {
    __shared__ float As[64][68];  // [row][k-local], stride 68 breaks bank conflicts
    __shared__ float Bs[64][68];  // [k-local][col]
    const int tid = threadIdx.x;
    const int m0 = blockIdx.x * 64;
    const int n0 = blockIdx.y * 64;
    const int tx = tid & 15, ty = tid >> 4;

    float acc[4][4] = {};

    for (int k0 = 0; k0 < 128; k0 += 64) {
        // load A tile 64x64 (1024 float4, 4 iters)
#pragma unroll
        for (int it = 0; it < 4; ++it) {
            int idx = it * 256 + tid;
            int r = idx >> 4;
            int c4 = (idx & 15) << 2;
            float4 v = make_float4(0.f, 0.f, 0.f, 0.f);
            if (m0 + r < n)
                v = *(const float4*)(X + (size_t)(m0 + r) * 128 + k0 + c4);
            *(float4*)&As[r][c4] = v;
        }
        // load B tile 64x64
#pragma unroll
        for (int it = 0; it < 4; ++it) {
            int idx = it * 256 + tid;
            int kk = idx >> 4;
            int c4 = (idx & 15) << 2;
            float4 v = *(const float4*)(W + (size_t)(k0 + kk) * OUT + n0 + c4);
            *(float4*)&Bs[kk][c4] = v;
        }
        __syncthreads();

#pragma unroll 8
        for (int k = 0; k < 64; ++k) {
            float a0 = As[ty * 4 + 0][k];
            float a1 = As[ty * 4 + 1][k];
            float a2 = As[ty * 4 + 2][k];
            float a3 = As[ty * 4 + 3][k];
            float4 b = *(const float4*)&Bs[k][tx * 4];
            acc[0][0] += a0 * b.x; acc[0][1] += a0 * b.y; acc[0][2] += a0 * b.z; acc[0][3] += a0 * b.w;
            acc[1][0] += a1 * b.x; acc[1][1] += a1 * b.y; acc[1][2] += a1 * b.z; acc[1][3] += a1 * b.w;
            acc[2][0] += a2 * b.x; acc[2][1] += a2 * b.y; acc[2][2] += a2 * b.z; acc[2][3] += a2 * b.w;
            acc[3][0] += a3 * b.x; acc[3][1] += a3 * b.y; acc[3][2] += a3 * b.z; acc[3][3] += a3 * b.w;
        }
        __syncthreads();
    }

#pragma unroll
    for (int i = 0; i < 4; ++i) {
        int r = m0 + ty * 4 + i;
        if (r < n) {
            float4 v = make_float4(acc[i][0], acc[i][1], acc[i][2], acc[i][3]);
            *(float4*)(C + (size_t)r * OUT + n0 + tx * 4) = v;
        }
    }
}

// ---------------------------------------------------------------------------
// Aggregation: one wave per node. lane owns dim lane (and lane+64 when D=128).
// out[i] = sum_e norm_e * T[src_e] + bias, optional ReLU. No atomics.
// ---------------------------------------------------------------------------
template <int D, bool RELU>
__global__ __launch_bounds__(256) void k_aggregate(const float* __restrict__ T,
                                                   const int* __restrict__ offs,
                                                   const int* __restrict__ esrc,
                                                   const float* __restrict__ enorm,
                                                   const float* __restrict__ bias,
                                                   float* __restrict__ out, int n) {
    int wid = (blockIdx.x * blockDim.x + threadIdx.x) >> 6;  // node id
    int lane = threadIdx.x & 63;
    if (wid >= n) return;
    int beg = offs[wid];
    int end = offs[wid + 1];

    float acc0 = 0.f, acc1 = 0.f;
    int e = beg;
    for (; e + 1 < end; e += 2) {
        int s0 = esrc[e];
        int s1 = esrc[e + 1];
        float w0 = enorm[e];
        float w1 = enorm[e + 1];
        const float* r0 = T + (size_t)s0 * D;
        const float* r1 = T + (size_t)s1 * D;
        acc0 += w0 * r0[lane];
        if (D == 128) acc1 += w0 * r0[lane + 64];
        acc0 += w1 * r1[lane];
        if (D == 128) acc1 += w1 * r1[lane + 64];
    }
    if (e < end) {
        int s = esrc[e];
        float w = enorm[e];
        const float* r = T + (size_t)s * D;
        acc0 += w * r[lane];
        if (D == 128) acc1 += w * r[lane + 64];
    }

    acc0 += bias[lane];
    if (RELU) acc0 = fmaxf(acc0, 0.f);
    out[(size_t)wid * D + lane] = acc0;
    if (D == 128) {
        acc1 += bias[lane + 64];
        if (RELU) acc1 = fmaxf(acc1, 0.f);
        out[(size_t)wid * D + lane + 64] = acc1;
    }
}

// ---------------------------------------------------------------------------

extern "C" void kernel_launch(void* const* d_in, const int* in_sizes, int n_in,
                              void* d_out, int out_size, void* d_ws, size_t ws_size,
                              hipStream_t stream) {
    const int n = in_sizes[0] / 128;   // 50000
    const int E = in_sizes[1] / 2;     // 800000

    const float* x  = (const float*)d_in[0];
    const int*   ei = (const int*)d_in[1];
    const float* W1 = (const float*)d_in[2];
    const float* b1 = (const float*)d_in[3];
    const float* W2 = (const float*)d_in[4];
    const float* b2 = (const float*)d_in[5];
    const float* W3 = (const float*)d_in[6];
    const float* b3 = (const float*)d_in[7];
    const int* src = ei;        // edge_index[0]
    const int* dst = ei + E;    // edge_index[1]
    float* out = (float*)d_out;

    // workspace carve-up (256B aligned)
    char* w = (char*)d_ws;
    auto alloc = [&](size_t bytes) {
        char* p = w;
        w += (bytes + 255) & ~(size_t)255;
        return p;
    };
    int*   deg    = (int*)alloc((size_t)n * 4);
    int*   cursor = (int*)alloc((size_t)n * 4);
    int*   offs   = (int*)alloc((size_t)(n + 1) * 4);
    int*   bsum   = (int*)alloc(256 * 4);
    float* dinv   = (float*)alloc((size_t)n * 4);
    int*   esrc   = (int*)alloc((size_t)(E + n) * 4);
    float* enorm  = (float*)alloc((size_t)(E + n) * 4);
    float* A      = (float*)alloc((size_t)n * 128 * 4);
    float* B      = (float*)alloc((size_t)n * 128 * 4);

    const int nb = (n + 255) / 256;  // 196 (<=256, fits single-block scan)

    // ---- CSR build (degree/norm shared by all 3 layers) ----
    k_init<<<nb, 256, 0, stream>>>(deg, cursor, n);
    k_hist<<<(E + 255) / 256, 256, 0, stream>>>(dst, E, deg);
    k_scan_block<<<nb, 256, 0, stream>>>(deg, offs, bsum, dinv, n);
    k_scan_bsum<<<1, 256, 0, stream>>>(bsum, nb);
    k_add_bsum<<<nb, 256, 0, stream>>>(offs, bsum, n, E + n);
    k_fill<<<(E + n + 255) / 256, 256, 0, stream>>>(src, dst, E, n, offs, cursor,
                                                    dinv, esrc, enorm);

    // ---- 3 GCN layers ----
    const int agg_blocks = (n * 64 + 255) / 256;  // one wave per node
    dim3 g128((n + 63) / 64, 2);
    dim3 g64((n + 63) / 64, 1);

    k_gemm<128><<<g128, 256, 0, stream>>>(x, W1, A, n);
    k_aggregate<128, true><<<agg_blocks, 256, 0, stream>>>(A, offs, esrc, enorm, b1, B, n);

    k_gemm<128><<<g128, 256, 0, stream>>>(B, W2, A, n);
    k_aggregate<128, true><<<agg_blocks, 256, 0, stream>>>(A, offs, esrc, enorm, b2, B, n);

    k_gemm<64><<<g64, 256, 0, stream>>>(B, W3, A, n);
    k_aggregate<64, false><<<agg_blocks, 256, 0, stream>>>(A, offs, esrc, enorm, b3, out, n);
}

// Round 2
// 325.844 us; speedup vs baseline: 1.0666x; 1.0666x over previous
//
#include <hip/hip_runtime.h>

// ---------------------------------------------------------------------------
// GCN 3-layer forward. fp32 throughout (no fp32 MFMA on CDNA4 -> vector GEMM).
// CSR-by-dst built once per launch (rows padded to multiple of 8 edges so the
// aggregation loop is tail-free and metadata loads are int4/float4-aligned).
// ---------------------------------------------------------------------------

// zero padded CSR arrays + init degree (1 = self-loop)
__global__ void k_init(int* __restrict__ deg, int n,
                       int* __restrict__ esrc, float* __restrict__ enorm, int cap) {
    int i = blockIdx.x * blockDim.x + threadIdx.x;
    if (i < n) deg[i] = 1;
    if (i < cap) { esrc[i] = 0; enorm[i] = 0.f; }
}

__global__ void k_hist(const int* __restrict__ dst, int E, int* __restrict__ deg) {
    int e = blockIdx.x * blockDim.x + threadIdx.x;
    if (e < E) atomicAdd(&deg[dst[e]], 1);
}

// per-block exclusive scan of padded degree (256 elems) + block sums; dinv = deg^-0.5
__global__ void k_scan_block(const int* __restrict__ deg, int* __restrict__ offs,
                             int* __restrict__ bsum, float* __restrict__ dinv, int n) {
    __shared__ int sm[256];
    int tid = threadIdx.x;
    int i = blockIdx.x * 256 + tid;
    int v = (i < n) ? deg[i] : 0;
    int pv = (i < n) ? ((v + 7) & ~7) : 0;   // pad each row to multiple of 8
    if (i < n) dinv[i] = rsqrtf((float)v);
    sm[tid] = pv;
    __syncthreads();
    for (int off = 1; off < 256; off <<= 1) {
        int t = (tid >= off) ? sm[tid - off] : 0;
        __syncthreads();
        sm[tid] += t;
        __syncthreads();
    }
    if (i < n) offs[i] = sm[tid] - pv;           // exclusive within block
    if (tid == 255) bsum[blockIdx.x] = sm[255];  // block total
}

// single-block exclusive scan of block sums (nb <= 256); writes grand total to offs[n]
__global__ void k_scan_bsum(int* __restrict__ bsum, int nb, int* __restrict__ offs, int n) {
    __shared__ int sm[256];
    int tid = threadIdx.x;
    int v = (tid < nb) ? bsum[tid] : 0;
    sm[tid] = v;
    __syncthreads();
    for (int off = 1; off < 256; off <<= 1) {
        int t = (tid >= off) ? sm[tid - off] : 0;
        __syncthreads();
        sm[tid] += t;
        __syncthreads();
    }
    if (tid < nb) bsum[tid] = sm[tid] - v;       // exclusive
    if (tid == 255) offs[n] = sm[255];           // grand total (padded)
}

// finalize offs and seed cursor = offs (k_fill then needs only one atomic)
__global__ void k_add_bsum(int* __restrict__ offs, const int* __restrict__ bsum,
                           int* __restrict__ cursor, int n) {
    int i = blockIdx.x * blockDim.x + threadIdx.x;
    if (i < n) {
        int o = offs[i] + bsum[i >> 8];
        offs[i] = o;
        cursor[i] = o;
    }
}

// scatter edges into CSR slots; norm precomputed once (same for all 3 layers)
__global__ void k_fill(const int* __restrict__ src, const int* __restrict__ dst,
                       int E, int n, int* __restrict__ cursor,
                       const float* __restrict__ dinv,
                       int* __restrict__ esrc, float* __restrict__ enorm) {
    int e = blockIdx.x * blockDim.x + threadIdx.x;
    int tot = E + n;
    if (e >= tot) return;
    int s = (e < E) ? src[e] : (e - E);
    int d = (e < E) ? dst[e] : (e - E);
    int pos = atomicAdd(&cursor[d], 1);
    esrc[pos] = s;
    enorm[pos] = dinv[s] * dinv[d];
}

// ---------------------------------------------------------------------------
// fp32 tiled GEMM: C[n][OUT] = X[n][128] @ W[128][OUT].
// BM=64, BN=OUT. 256 threads as 16x16, thread tile 4 rows x (OUT/16) cols with
// split-column mapping {tx*4, 64+tx*4} -> all LDS fragment reads are 16B-stride
// b128 (conflict-free / broadcast). A staged transposed As[k][m] so the A
// fragment is one b128. 3 ds_read_b128 per thread-k for 32 FMAs (OUT=128).
// ---------------------------------------------------------------------------
template <int OUT>
__global__ __launch_bounds__(256) void k_gemm(const float* __restrict__ X,
                                              const float* __restrict__ W,
                                              float* __restrict__ C, int n) {
    constexpr int NT = OUT / 16;        // cols per thread: 8 or 4
    __shared__ float As[32][68];        // [k][m], padded
    __shared__ float Bs[32][OUT + 4];   // [k][col], padded
    const int tid = threadIdx.x;
    const int tx = tid & 15, ty = tid >> 4;
    const int m0 = blockIdx.x * 64;

    float acc[4][NT] = {};

    for (int k0 = 0; k0 < 128; k0 += 32) {
        // stage A transposed: 64 rows x 32 k = 512 float4 -> 2 iters
#pragma unroll
        for (int it = 0; it < 2; ++it) {
            int idx = it * 256 + tid;
            int r = idx >> 3;
            int c4 = (idx & 7) << 2;
            float4 v = make_float4(0.f, 0.f, 0.f, 0.f);
            if (m0 + r < n)
                v = *(const float4*)(X + (size_t)(m0 + r) * 128 + k0 + c4);
            As[c4 + 0][r] = v.x;
            As[c4 + 1][r] = v.y;
            As[c4 + 2][r] = v.z;
            As[c4 + 3][r] = v.w;
        }
        // stage B: 32 k x OUT floats
        constexpr int F4R = OUT / 4;    // float4 per W row
#pragma unroll
        for (int it = 0; it < (32 * F4R) / 256; ++it) {
            int idx = it * 256 + tid;
            int kk = idx / F4R;
            int c4 = (idx % F4R) << 2;
            *(float4*)&Bs[kk][c4] = *(const float4*)(W + (size_t)(k0 + kk) * OUT + c4);
        }
        __syncthreads();

#pragma unroll
        for (int k = 0; k < 32; ++k) {
            float4 a = *(const float4*)&As[k][ty * 4];
            float4 b0 = *(const float4*)&Bs[k][tx * 4];
            float av[4] = {a.x, a.y, a.z, a.w};
#pragma unroll
            for (int i = 0; i < 4; ++i) {
                acc[i][0] += av[i] * b0.x;
                acc[i][1] += av[i] * b0.y;
                acc[i][2] += av[i] * b0.z;
                acc[i][3] += av[i] * b0.w;
            }
            if constexpr (OUT == 128) {
                float4 b1 = *(const float4*)&Bs[k][64 + tx * 4];
#pragma unroll
                for (int i = 0; i < 4; ++i) {
                    acc[i][4] += av[i] * b1.x;
                    acc[i][5] += av[i] * b1.y;
                    acc[i][6] += av[i] * b1.z;
                    acc[i][7] += av[i] * b1.w;
                }
            }
        }
        __syncthreads();
    }

#pragma unroll
    for (int i = 0; i < 4; ++i) {
        int r = m0 + ty * 4 + i;
        if (r < n) {
            *(float4*)(C + (size_t)r * OUT + tx * 4) =
                make_float4(acc[i][0], acc[i][1], acc[i][2], acc[i][3]);
            if constexpr (OUT == 128)
                *(float4*)(C + (size_t)r * OUT + 64 + tx * 4) =
                    make_float4(acc[i][4], acc[i][5], acc[i][6], acc[i][7]);
        }
    }
}

// ---------------------------------------------------------------------------
// Aggregation, one wave per node, rows padded to x8 (pad: src=0, norm=0).
// D=128: lane owns float2 -> one load instruction covers a whole 512B row.
// 8 edges in flight per iteration. No atomics, coalesced writes.
// ---------------------------------------------------------------------------
template <bool RELU>
__global__ __launch_bounds__(256) void k_agg128(const float* __restrict__ T,
                                                const int* __restrict__ offs,
                                                const int* __restrict__ esrc,
                                                const float* __restrict__ enorm,
                                                const float* __restrict__ bias,
                                                float* __restrict__ out, int n) {
    int wid = blockIdx.x * 4 + (threadIdx.x >> 6);
    int lane = threadIdx.x & 63;
    if (wid >= n) return;
    int beg = offs[wid];
    int end = offs[wid + 1];

    const float* Tl = T + (lane << 1);
    float a0 = 0.f, a1 = 0.f;
    for (int e = beg; e < end; e += 8) {
        int4 s0 = *(const int4*)(esrc + e);
        int4 s1 = *(const int4*)(esrc + e + 4);
        float4 w0 = *(const float4*)(enorm + e);
        float4 w1 = *(const float4*)(enorm + e + 4);
        float2 r0 = *(const float2*)(Tl + (size_t)s0.x * 128);
        float2 r1 = *(const float2*)(Tl + (size_t)s0.y * 128);
        float2 r2 = *(const float2*)(Tl + (size_t)s0.z * 128);
        float2 r3 = *(const float2*)(Tl + (size_t)s0.w * 128);
        float2 r4 = *(const float2*)(Tl + (size_t)s1.x * 128);
        float2 r5 = *(const float2*)(Tl + (size_t)s1.y * 128);
        float2 r6 = *(const float2*)(Tl + (size_t)s1.z * 128);
        float2 r7 = *(const float2*)(Tl + (size_t)s1.w * 128);
        a0 += w0.x * r0.x; a1 += w0.x * r0.y;
        a0 += w0.y * r1.x; a1 += w0.y * r1.y;
        a0 += w0.z * r2.x; a1 += w0.z * r2.y;
        a0 += w0.w * r3.x; a1 += w0.w * r3.y;
        a0 += w1.x * r4.x; a1 += w1.x * r4.y;
        a0 += w1.y * r5.x; a1 += w1.y * r5.y;
        a0 += w1.z * r6.x; a1 += w1.z * r6.y;
        a0 += w1.w * r7.x; a1 += w1.w * r7.y;
    }

    float2 b = *(const float2*)(bias + (lane << 1));
    a0 += b.x; a1 += b.y;
    if (RELU) { a0 = fmaxf(a0, 0.f); a1 = fmaxf(a1, 0.f); }
    *(float2*)(out + (size_t)wid * 128 + (lane << 1)) = make_float2(a0, a1);
}

__global__ __launch_bounds__(256) void k_agg64(const float* __restrict__ T,
                                               const int* __restrict__ offs,
                                               const int* __restrict__ esrc,
                                               const float* __restrict__ enorm,
                                               const float* __restrict__ bias,
                                               float* __restrict__ out, int n) {
    int wid = blockIdx.x * 4 + (threadIdx.x >> 6);
    int lane = threadIdx.x & 63;
    if (wid >= n) return;
    int beg = offs[wid];
    int end = offs[wid + 1];

    const float* Tl = T + lane;
    float a0 = 0.f;
    for (int e = beg; e < end; e += 8) {
        int4 s0 = *(const int4*)(esrc + e);
        int4 s1 = *(const int4*)(esrc + e + 4);
        float4 w0 = *(const float4*)(enorm + e);
        float4 w1 = *(const float4*)(enorm + e + 4);
        float r0 = Tl[(size_t)s0.x * 64];
        float r1 = Tl[(size_t)s0.y * 64];
        float r2 = Tl[(size_t)s0.z * 64];
        float r3 = Tl[(size_t)s0.w * 64];
        float r4 = Tl[(size_t)s1.x * 64];
        float r5 = Tl[(size_t)s1.y * 64];
        float r6 = Tl[(size_t)s1.z * 64];
        float r7 = Tl[(size_t)s1.w * 64];
        a0 += w0.x * r0 + w0.y * r1 + w0.z * r2 + w0.w * r3;
        a0 += w1.x * r4 + w1.y * r5 + w1.z * r6 + w1.w * r7;
    }

    a0 += bias[lane];
    out[(size_t)wid * 64 + lane] = a0;
}

// ---------------------------------------------------------------------------

extern "C" void kernel_launch(void* const* d_in, const int* in_sizes, int n_in,
                              void* d_out, int out_size, void* d_ws, size_t ws_size,
                              hipStream_t stream) {
    const int n = in_sizes[0] / 128;   // 50000
    const int E = in_sizes[1] / 2;     // 800000

    const float* x  = (const float*)d_in[0];
    const int*   ei = (const int*)d_in[1];
    const float* W1 = (const float*)d_in[2];
    const float* b1 = (const float*)d_in[3];
    const float* W2 = (const float*)d_in[4];
    const float* b2 = (const float*)d_in[5];
    const float* W3 = (const float*)d_in[6];
    const float* b3 = (const float*)d_in[7];
    const int* src = ei;        // edge_index[0]
    const int* dst = ei + E;    // edge_index[1]
    float* out = (float*)d_out;

    const int cap = E + 8 * n;  // max padded edge slots (sum of (deg+7)&~7)

    // workspace carve-up (256B aligned)
    char* w = (char*)d_ws;
    auto alloc = [&](size_t bytes) {
        char* p = w;
        w += (bytes + 255) & ~(size_t)255;
        return p;
    };
    int*   deg    = (int*)alloc((size_t)n * 4);
    int*   cursor = (int*)alloc((size_t)n * 4);
    int*   offs   = (int*)alloc((size_t)(n + 1) * 4);
    int*   bsum   = (int*)alloc(256 * 4);
    float* dinv   = (float*)alloc((size_t)n * 4);
    int*   esrc   = (int*)alloc((size_t)cap * 4);
    float* enorm  = (float*)alloc((size_t)cap * 4);
    float* A      = (float*)alloc((size_t)n * 128 * 4);
    float* B      = (float*)alloc((size_t)n * 128 * 4);

    const int nb = (n + 255) / 256;  // 196 (<=256, fits single-block scan)

    // ---- CSR build (degree/norm shared by all 3 layers) ----
    k_init<<<(cap + 255) / 256, 256, 0, stream>>>(deg, n, esrc, enorm, cap);
    k_hist<<<(E + 255) / 256, 256, 0, stream>>>(dst, E, deg);
    k_scan_block<<<nb, 256, 0, stream>>>(deg, offs, bsum, dinv, n);
    k_scan_bsum<<<1, 256, 0, stream>>>(bsum, nb, offs, n);
    k_add_bsum<<<nb, 256, 0, stream>>>(offs, bsum, cursor, n);
    k_fill<<<(E + n + 255) / 256, 256, 0, stream>>>(src, dst, E, n, cursor,
                                                    dinv, esrc, enorm);

    // ---- 3 GCN layers ----
    const int agg_blocks = (n + 3) / 4;     // one wave per node, 4 waves/block
    const int gemm_blocks = (n + 63) / 64;

    k_gemm<128><<<gemm_blocks, 256, 0, stream>>>(x, W1, A, n);
    k_agg128<true><<<agg_blocks, 256, 0, stream>>>(A, offs, esrc, enorm, b1, B, n);

    k_gemm<128><<<gemm_blocks, 256, 0, stream>>>(B, W2, A, n);
    k_agg128<true><<<agg_blocks, 256, 0, stream>>>(A, offs, esrc, enorm, b2, B, n);

    k_gemm<64><<<gemm_blocks, 256, 0, stream>>>(B, W3, A, n);
    k_agg64<<<agg_blocks, 256, 0, stream>>>(A, offs, esrc, enorm, b3, out, n);
}

// Round 3
// 281.830 us; speedup vs baseline: 1.2332x; 1.1562x over previous
//
#include <hip/hip_runtime.h>
#include <hip/hip_bf16.h>

// ---------------------------------------------------------------------------
// GCN 3-layer forward. GEMMs in fp32 (no fp32 MFMA on CDNA4). The per-layer
// GEMM output t = h @ W is stored in bf16 and is the ONLY thing gathered by
// the aggregation pass (halves random-gather traffic; 12.8MB fits aggregate
// L2). Accumulation, bias, ReLU, next-layer GEMM input all stay fp32.
// CSR-by-dst built once per launch, rows padded to x8 (pad: src=0, norm=0).
// ---------------------------------------------------------------------------

__device__ __forceinline__ float bfu_lo(uint v) { return __uint_as_float(v << 16); }
__device__ __forceinline__ float bfu_hi(uint v) { return __uint_as_float(v & 0xffff0000u); }

// zero padded CSR arrays + init degree (1 = self-loop)
__global__ void k_init(int* __restrict__ deg, int n,
                       int* __restrict__ esrc, float* __restrict__ enorm, int cap) {
    int i = blockIdx.x * blockDim.x + threadIdx.x;
    if (i < n) deg[i] = 1;
    if (i < cap) { esrc[i] = 0; enorm[i] = 0.f; }
}

__global__ void k_hist(const int* __restrict__ dst, int E, int* __restrict__ deg) {
    int e = blockIdx.x * blockDim.x + threadIdx.x;
    if (e < E) atomicAdd(&deg[dst[e]], 1);
}

// per-block exclusive scan of padded degree (256 elems) + block sums; dinv = deg^-0.5
__global__ void k_scan_block(const int* __restrict__ deg, int* __restrict__ offs,
                             int* __restrict__ bsum, float* __restrict__ dinv, int n) {
    __shared__ int sm[256];
    int tid = threadIdx.x;
    int i = blockIdx.x * 256 + tid;
    int v = (i < n) ? deg[i] : 0;
    int pv = (i < n) ? ((v + 7) & ~7) : 0;   // pad each row to multiple of 8
    if (i < n) dinv[i] = rsqrtf((float)v);
    sm[tid] = pv;
    __syncthreads();
    for (int off = 1; off < 256; off <<= 1) {
        int t = (tid >= off) ? sm[tid - off] : 0;
        __syncthreads();
        sm[tid] += t;
        __syncthreads();
    }
    if (i < n) offs[i] = sm[tid] - pv;           // exclusive within block
    if (tid == 255) bsum[blockIdx.x] = sm[255];  // block total
}

// single-block exclusive scan of block sums (nb <= 256); writes grand total to offs[n]
__global__ void k_scan_bsum(int* __restrict__ bsum, int nb, int* __restrict__ offs, int n) {
    __shared__ int sm[256];
    int tid = threadIdx.x;
    int v = (tid < nb) ? bsum[tid] : 0;
    sm[tid] = v;
    __syncthreads();
    for (int off = 1; off < 256; off <<= 1) {
        int t = (tid >= off) ? sm[tid - off] : 0;
        __syncthreads();
        sm[tid] += t;
        __syncthreads();
    }
    if (tid < nb) bsum[tid] = sm[tid] - v;       // exclusive
    if (tid == 255) offs[n] = sm[255];           // grand total (padded)
}

// finalize offs and seed cursor = offs (k_fill then needs only one atomic)
__global__ void k_add_bsum(int* __restrict__ offs, const int* __restrict__ bsum,
                           int* __restrict__ cursor, int n) {
    int i = blockIdx.x * blockDim.x + threadIdx.x;
    if (i < n) {
        int o = offs[i] + bsum[i >> 8];
        offs[i] = o;
        cursor[i] = o;
    }
}

// scatter edges into CSR slots; norm precomputed once (same for all 3 layers)
__global__ void k_fill(const int* __restrict__ src, const int* __restrict__ dst,
                       int E, int n, int* __restrict__ cursor,
                       const float* __restrict__ dinv,
                       int* __restrict__ esrc, float* __restrict__ enorm) {
    int e = blockIdx.x * blockDim.x + threadIdx.x;
    int tot = E + n;
    if (e >= tot) return;
    int s = (e < E) ? src[e] : (e - E);
    int d = (e < E) ? dst[e] : (e - E);
    int pos = atomicAdd(&cursor[d], 1);
    esrc[pos] = s;
    enorm[pos] = dinv[s] * dinv[d];
}

// ---------------------------------------------------------------------------
// fp32 tiled GEMM: T[n][OUT] = X[n][128] @ W[128][OUT], output stored bf16.
// BM=64, BN=OUT. 256 threads as 16x16, thread tile 4 rows x (OUT/16) cols,
// split-column mapping {tx*4, 64+tx*4}. A staged transposed As[k][m].
// ---------------------------------------------------------------------------
template <int OUT>
__global__ __launch_bounds__(256) void k_gemm(const float* __restrict__ X,
                                              const float* __restrict__ W,
                                              __hip_bfloat16* __restrict__ T, int n) {
    constexpr int NT = OUT / 16;        // cols per thread: 8 or 4
    __shared__ float As[32][68];        // [k][m], padded
    __shared__ float Bs[32][OUT + 4];   // [k][col], padded
    const int tid = threadIdx.x;
    const int tx = tid & 15, ty = tid >> 4;
    const int m0 = blockIdx.x * 64;

    float acc[4][NT] = {};

    for (int k0 = 0; k0 < 128; k0 += 32) {
        // stage A transposed: 64 rows x 32 k = 512 float4 -> 2 iters
#pragma unroll
        for (int it = 0; it < 2; ++it) {
            int idx = it * 256 + tid;
            int r = idx >> 3;
            int c4 = (idx & 7) << 2;
            float4 v = make_float4(0.f, 0.f, 0.f, 0.f);
            if (m0 + r < n)
                v = *(const float4*)(X + (size_t)(m0 + r) * 128 + k0 + c4);
            As[c4 + 0][r] = v.x;
            As[c4 + 1][r] = v.y;
            As[c4 + 2][r] = v.z;
            As[c4 + 3][r] = v.w;
        }
        // stage B: 32 k x OUT floats
        constexpr int F4R = OUT / 4;    // float4 per W row
#pragma unroll
        for (int it = 0; it < (32 * F4R) / 256; ++it) {
            int idx = it * 256 + tid;
            int kk = idx / F4R;
            int c4 = (idx % F4R) << 2;
            *(float4*)&Bs[kk][c4] = *(const float4*)(W + (size_t)(k0 + kk) * OUT + c4);
        }
        __syncthreads();

#pragma unroll
        for (int k = 0; k < 32; ++k) {
            float4 a = *(const float4*)&As[k][ty * 4];
            float4 b0 = *(const float4*)&Bs[k][tx * 4];
            float av[4] = {a.x, a.y, a.z, a.w};
#pragma unroll
            for (int i = 0; i < 4; ++i) {
                acc[i][0] += av[i] * b0.x;
                acc[i][1] += av[i] * b0.y;
                acc[i][2] += av[i] * b0.z;
                acc[i][3] += av[i] * b0.w;
            }
            if constexpr (OUT == 128) {
                float4 b1 = *(const float4*)&Bs[k][64 + tx * 4];
#pragma unroll
                for (int i = 0; i < 4; ++i) {
                    acc[i][4] += av[i] * b1.x;
                    acc[i][5] += av[i] * b1.y;
                    acc[i][6] += av[i] * b1.z;
                    acc[i][7] += av[i] * b1.w;
                }
            }
        }
        __syncthreads();
    }

#pragma unroll
    for (int i = 0; i < 4; ++i) {
        int r = m0 + ty * 4 + i;
        if (r < n) {
            union { __hip_bfloat16 h[4]; uint2 u; } p0;
#pragma unroll
            for (int j = 0; j < 4; ++j) p0.h[j] = __float2bfloat16(acc[i][j]);
            *(uint2*)(T + (size_t)r * OUT + tx * 4) = p0.u;
            if constexpr (OUT == 128) {
                union { __hip_bfloat16 h[4]; uint2 u; } p1;
#pragma unroll
                for (int j = 0; j < 4; ++j) p1.h[j] = __float2bfloat16(acc[i][4 + j]);
                *(uint2*)(T + (size_t)r * OUT + 64 + tx * 4) = p1.u;
            }
        }
    }
}

// ---------------------------------------------------------------------------
// Aggregation, one wave per node, rows padded to x8. Gathers bf16 rows,
// accumulates fp32. D=128: lane owns dims {2*lane, 2*lane+1} -> one 4B load
// per edge covers the whole 256B row per wave. Writes fp32 (+bias, ReLU).
// ---------------------------------------------------------------------------
template <bool RELU>
__global__ __launch_bounds__(256) void k_agg128(const __hip_bfloat16* __restrict__ T,
                                                const int* __restrict__ offs,
                                                const int* __restrict__ esrc,
                                                const float* __restrict__ enorm,
                                                const float* __restrict__ bias,
                                                float* __restrict__ out, int n) {
    int wid = blockIdx.x * 4 + (threadIdx.x >> 6);
    int lane = threadIdx.x & 63;
    if (wid >= n) return;
    int beg = offs[wid];
    int end = offs[wid + 1];

    const uint* Tl = (const uint*)T + lane;   // lane's 2-dim slot within a row
    float a0 = 0.f, a1 = 0.f;
    for (int e = beg; e < end; e += 8) {
        int4 s0 = *(const int4*)(esrc + e);
        int4 s1 = *(const int4*)(esrc + e + 4);
        float4 w0 = *(const float4*)(enorm + e);
        float4 w1 = *(const float4*)(enorm + e + 4);
        uint r0 = Tl[(size_t)s0.x * 64];
        uint r1 = Tl[(size_t)s0.y * 64];
        uint r2 = Tl[(size_t)s0.z * 64];
        uint r3 = Tl[(size_t)s0.w * 64];
        uint r4 = Tl[(size_t)s1.x * 64];
        uint r5 = Tl[(size_t)s1.y * 64];
        uint r6 = Tl[(size_t)s1.z * 64];
        uint r7 = Tl[(size_t)s1.w * 64];
        a0 += w0.x * bfu_lo(r0); a1 += w0.x * bfu_hi(r0);
        a0 += w0.y * bfu_lo(r1); a1 += w0.y * bfu_hi(r1);
        a0 += w0.z * bfu_lo(r2); a1 += w0.z * bfu_hi(r2);
        a0 += w0.w * bfu_lo(r3); a1 += w0.w * bfu_hi(r3);
        a0 += w1.x * bfu_lo(r4); a1 += w1.x * bfu_hi(r4);
        a0 += w1.y * bfu_lo(r5); a1 += w1.y * bfu_hi(r5);
        a0 += w1.z * bfu_lo(r6); a1 += w1.z * bfu_hi(r6);
        a0 += w1.w * bfu_lo(r7); a1 += w1.w * bfu_hi(r7);
    }

    float2 b = *(const float2*)(bias + (lane << 1));
    a0 += b.x; a1 += b.y;
    if (RELU) { a0 = fmaxf(a0, 0.f); a1 = fmaxf(a1, 0.f); }
    *(float2*)(out + (size_t)wid * 128 + (lane << 1)) = make_float2(a0, a1);
}

__global__ __launch_bounds__(256) void k_agg64(const __hip_bfloat16* __restrict__ T,
                                               const int* __restrict__ offs,
                                               const int* __restrict__ esrc,
                                               const float* __restrict__ enorm,
                                               const float* __restrict__ bias,
                                               float* __restrict__ out, int n) {
    int wid = blockIdx.x * 4 + (threadIdx.x >> 6);
    int lane = threadIdx.x & 63;
    if (wid >= n) return;
    int beg = offs[wid];
    int end = offs[wid + 1];

    const ushort* Tl = (const ushort*)T + lane;
    float a0 = 0.f;
    for (int e = beg; e < end; e += 8) {
        int4 s0 = *(const int4*)(esrc + e);
        int4 s1 = *(const int4*)(esrc + e + 4);
        float4 w0 = *(const float4*)(enorm + e);
        float4 w1 = *(const float4*)(enorm + e + 4);
        float r0 = __uint_as_float((uint)Tl[(size_t)s0.x * 64] << 16);
        float r1 = __uint_as_float((uint)Tl[(size_t)s0.y * 64] << 16);
        float r2 = __uint_as_float((uint)Tl[(size_t)s0.z * 64] << 16);
        float r3 = __uint_as_float((uint)Tl[(size_t)s0.w * 64] << 16);
        float r4 = __uint_as_float((uint)Tl[(size_t)s1.x * 64] << 16);
        float r5 = __uint_as_float((uint)Tl[(size_t)s1.y * 64] << 16);
        float r6 = __uint_as_float((uint)Tl[(size_t)s1.z * 64] << 16);
        float r7 = __uint_as_float((uint)Tl[(size_t)s1.w * 64] << 16);
        a0 += w0.x * r0 + w0.y * r1 + w0.z * r2 + w0.w * r3;
        a0 += w1.x * r4 + w1.y * r5 + w1.z * r6 + w1.w * r7;
    }

    a0 += bias[lane];
    out[(size_t)wid * 64 + lane] = a0;
}

// ---------------------------------------------------------------------------

extern "C" void kernel_launch(void* const* d_in, const int* in_sizes, int n_in,
                              void* d_out, int out_size, void* d_ws, size_t ws_size,
                              hipStream_t stream) {
    const int n = in_sizes[0] / 128;   // 50000
    const int E = in_sizes[1] / 2;     // 800000

    const float* x  = (const float*)d_in[0];
    const int*   ei = (const int*)d_in[1];
    const float* W1 = (const float*)d_in[2];
    const float* b1 = (const float*)d_in[3];
    const float* W2 = (const float*)d_in[4];
    const float* b2 = (const float*)d_in[5];
    const float* W3 = (const float*)d_in[6];
    const float* b3 = (const float*)d_in[7];
    const int* src = ei;        // edge_index[0]
    const int* dst = ei + E;    // edge_index[1]
    float* out = (float*)d_out;

    const int cap = E + 8 * n;  // max padded edge slots (sum of (deg+7)&~7)

    // workspace carve-up (256B aligned)
    char* w = (char*)d_ws;
    auto alloc = [&](size_t bytes) {
        char* p = w;
        w += (bytes + 255) & ~(size_t)255;
        return p;
    };
    int*   deg    = (int*)alloc((size_t)n * 4);
    int*   cursor = (int*)alloc((size_t)n * 4);
    int*   offs   = (int*)alloc((size_t)(n + 1) * 4);
    int*   bsum   = (int*)alloc(256 * 4);
    float* dinv   = (float*)alloc((size_t)n * 4);
    int*   esrc   = (int*)alloc((size_t)cap * 4);
    float* enorm  = (float*)alloc((size_t)cap * 4);
    __hip_bfloat16* tA = (__hip_bfloat16*)alloc((size_t)n * 128 * 2);  // gathered (bf16)
    float* hB     = (float*)alloc((size_t)n * 128 * 4);                // fp32 activations

    const int nb = (n + 255) / 256;  // 196 (<=256, fits single-block scan)

    // ---- CSR build (degree/norm shared by all 3 layers) ----
    k_init<<<(cap + 255) / 256, 256, 0, stream>>>(deg, n, esrc, enorm, cap);
    k_hist<<<(E + 255) / 256, 256, 0, stream>>>(dst, E, deg);
    k_scan_block<<<nb, 256, 0, stream>>>(deg, offs, bsum, dinv, n);
    k_scan_bsum<<<1, 256, 0, stream>>>(bsum, nb, offs, n);
    k_add_bsum<<<nb, 256, 0, stream>>>(offs, bsum, cursor, n);
    k_fill<<<(E + n + 255) / 256, 256, 0, stream>>>(src, dst, E, n, cursor,
                                                    dinv, esrc, enorm);

    // ---- 3 GCN layers ----
    const int agg_blocks = (n + 3) / 4;     // one wave per node, 4 waves/block
    const int gemm_blocks = (n + 63) / 64;

    k_gemm<128><<<gemm_blocks, 256, 0, stream>>>(x, W1, tA, n);
    k_agg128<true><<<agg_blocks, 256, 0, stream>>>(tA, offs, esrc, enorm, b1, hB, n);

    k_gemm<128><<<gemm_blocks, 256, 0, stream>>>(hB, W2, tA, n);
    k_agg128<true><<<agg_blocks, 256, 0, stream>>>(tA, offs, esrc, enorm, b2, hB, n);

    k_gemm<64><<<gemm_blocks, 256, 0, stream>>>(hB, W3, tA, n);
    k_agg64<<<agg_blocks, 256, 0, stream>>>(tA, offs, esrc, enorm, b3, out, n);
}

// Round 4
// 260.589 us; speedup vs baseline: 1.3337x; 1.0815x over previous
//
#include <hip/hip_runtime.h>
#include <hip/hip_bf16.h>

// ---------------------------------------------------------------------------
// GCN 3-layer forward. GEMMs fp32 (no fp32 MFMA on CDNA4). Per-layer GEMM
// output t = h @ W stored bf16 -> the only thing the aggregation gathers
// (12.8MB, L2-friendly). Accumulation/bias/ReLU/next GEMM input stay fp32.
// CSR-by-dst built once, rows padded to x8; edge metadata packed as int2
// {src, norm_bits} so the CSR fill does ONE 8B scatter store per edge.
// ---------------------------------------------------------------------------

__device__ __forceinline__ float bfu_lo(uint v) { return __uint_as_float(v << 16); }
__device__ __forceinline__ float bfu_hi(uint v) { return __uint_as_float(v & 0xffff0000u); }

// zero packed CSR array + init degree (1 = self-loop)
__global__ void k_init(int* __restrict__ deg, int n,
                       int2* __restrict__ ep, int cap) {
    int i = blockIdx.x * blockDim.x + threadIdx.x;
    if (i < n) deg[i] = 1;
    if (i < cap) ep[i] = make_int2(0, 0);   // src=0, norm=+0.0f
}

__global__ void k_hist(const int* __restrict__ dst, int E, int* __restrict__ deg) {
    int e = blockIdx.x * blockDim.x + threadIdx.x;
    if (e < E) atomicAdd(&deg[dst[e]], 1);
}

// per-block exclusive scan of padded degree (256 elems) + block sums; dinv = deg^-0.5
__global__ void k_scan_block(const int* __restrict__ deg, int* __restrict__ offs,
                             int* __restrict__ bsum, float* __restrict__ dinv, int n) {
    __shared__ int sm[256];
    int tid = threadIdx.x;
    int i = blockIdx.x * 256 + tid;
    int v = (i < n) ? deg[i] : 0;
    int pv = (i < n) ? ((v + 7) & ~7) : 0;   // pad each row to multiple of 8
    if (i < n) dinv[i] = rsqrtf((float)v);
    sm[tid] = pv;
    __syncthreads();
    for (int off = 1; off < 256; off <<= 1) {
        int t = (tid >= off) ? sm[tid - off] : 0;
        __syncthreads();
        sm[tid] += t;
        __syncthreads();
    }
    if (i < n) offs[i] = sm[tid] - pv;           // exclusive within block
    if (tid == 255) bsum[blockIdx.x] = sm[255];  // block total
}

// single-block exclusive scan of block sums (nb <= 256); writes grand total to offs[n]
__global__ void k_scan_bsum(int* __restrict__ bsum, int nb, int* __restrict__ offs, int n) {
    __shared__ int sm[256];
    int tid = threadIdx.x;
    int v = (tid < nb) ? bsum[tid] : 0;
    sm[tid] = v;
    __syncthreads();
    for (int off = 1; off < 256; off <<= 1) {
        int t = (tid >= off) ? sm[tid - off] : 0;
        __syncthreads();
        sm[tid] += t;
        __syncthreads();
    }
    if (tid < nb) bsum[tid] = sm[tid] - v;       // exclusive
    if (tid == 255) offs[n] = sm[255];           // grand total (padded)
}

// finalize offs and seed cursor = offs (k_fill then needs only one atomic)
__global__ void k_add_bsum(int* __restrict__ offs, const int* __restrict__ bsum,
                           int* __restrict__ cursor, int n) {
    int i = blockIdx.x * blockDim.x + threadIdx.x;
    if (i < n) {
        int o = offs[i] + bsum[i >> 8];
        offs[i] = o;
        cursor[i] = o;
    }
}

// scatter edges into CSR slots: ONE 8B store per edge {src, norm_bits}
__global__ void k_fill(const int* __restrict__ src, const int* __restrict__ dst,
                       int E, int n, int* __restrict__ cursor,
                       const float* __restrict__ dinv,
                       int2* __restrict__ ep) {
    int e = blockIdx.x * blockDim.x + threadIdx.x;
    int tot = E + n;
    if (e >= tot) return;
    int s = (e < E) ? src[e] : (e - E);
    int d = (e < E) ? dst[e] : (e - E);
    int pos = atomicAdd(&cursor[d], 1);
    ep[pos] = make_int2(s, __float_as_int(dinv[s] * dinv[d]));
}

// ---------------------------------------------------------------------------
// fp32 tiled GEMM: T[n][OUT] = X[n][128] @ W[128][OUT], output stored bf16.
// BM=64, BN=OUT. 256 threads as 16x16, thread tile 4 rows x (OUT/16) cols,
// split-column mapping {tx*4, 64+tx*4}. A staged transposed As[k][m].
// ---------------------------------------------------------------------------
template <int OUT>
__global__ __launch_bounds__(256) void k_gemm(const float* __restrict__ X,
                                              const float* __restrict__ W,
                                              __hip_bfloat16* __restrict__ T, int n) {
    constexpr int NT = OUT / 16;        // cols per thread: 8 or 4
    __shared__ float As[32][68];        // [k][m], padded
    __shared__ float Bs[32][OUT + 4];   // [k][col], padded
    const int tid = threadIdx.x;
    const int tx = tid & 15, ty = tid >> 4;
    const int m0 = blockIdx.x * 64;

    float acc[4][NT] = {};

    for (int k0 = 0; k0 < 128; k0 += 32) {
        // stage A transposed: 64 rows x 32 k = 512 float4 -> 2 iters
#pragma unroll
        for (int it = 0; it < 2; ++it) {
            int idx = it * 256 + tid;
            int r = idx >> 3;
            int c4 = (idx & 7) << 2;
            float4 v = make_float4(0.f, 0.f, 0.f, 0.f);
            if (m0 + r < n)
                v = *(const float4*)(X + (size_t)(m0 + r) * 128 + k0 + c4);
            As[c4 + 0][r] = v.x;
            As[c4 + 1][r] = v.y;
            As[c4 + 2][r] = v.z;
            As[c4 + 3][r] = v.w;
        }
        // stage B: 32 k x OUT floats
        constexpr int F4R = OUT / 4;    // float4 per W row
#pragma unroll
        for (int it = 0; it < (32 * F4R) / 256; ++it) {
            int idx = it * 256 + tid;
            int kk = idx / F4R;
            int c4 = (idx % F4R) << 2;
            *(float4*)&Bs[kk][c4] = *(const float4*)(W + (size_t)(k0 + kk) * OUT + c4);
        }
        __syncthreads();

#pragma unroll
        for (int k = 0; k < 32; ++k) {
            float4 a = *(const float4*)&As[k][ty * 4];
            float4 b0 = *(const float4*)&Bs[k][tx * 4];
            float av[4] = {a.x, a.y, a.z, a.w};
#pragma unroll
            for (int i = 0; i < 4; ++i) {
                acc[i][0] += av[i] * b0.x;
                acc[i][1] += av[i] * b0.y;
                acc[i][2] += av[i] * b0.z;
                acc[i][3] += av[i] * b0.w;
            }
            if constexpr (OUT == 128) {
                float4 b1 = *(const float4*)&Bs[k][64 + tx * 4];
#pragma unroll
                for (int i = 0; i < 4; ++i) {
                    acc[i][4] += av[i] * b1.x;
                    acc[i][5] += av[i] * b1.y;
                    acc[i][6] += av[i] * b1.z;
                    acc[i][7] += av[i] * b1.w;
                }
            }
        }
        __syncthreads();
    }

#pragma unroll
    for (int i = 0; i < 4; ++i) {
        int r = m0 + ty * 4 + i;
        if (r < n) {
            union { __hip_bfloat16 h[4]; uint2 u; } p0;
#pragma unroll
            for (int j = 0; j < 4; ++j) p0.h[j] = __float2bfloat16(acc[i][j]);
            *(uint2*)(T + (size_t)r * OUT + tx * 4) = p0.u;
            if constexpr (OUT == 128) {
                union { __hip_bfloat16 h[4]; uint2 u; } p1;
#pragma unroll
                for (int j = 0; j < 4; ++j) p1.h[j] = __float2bfloat16(acc[i][4 + j]);
                *(uint2*)(T + (size_t)r * OUT + 64 + tx * 4) = p1.u;
            }
        }
    }
}

// ---------------------------------------------------------------------------
// Aggregation, one wave per node, rows padded to x8 (pad: src=0, norm=0).
// Gathers bf16 rows, accumulates fp32. Metadata for the NEXT 8 edges is
// prefetched while the current 8 row-gathers are in flight (one memory
// round-trip per iteration instead of two). D=128: lane owns dims
// {2*lane, 2*lane+1} -> one 4B gather per edge covers the 256B row per wave.
// ---------------------------------------------------------------------------
template <bool RELU>
__global__ __launch_bounds__(256) void k_agg128(const __hip_bfloat16* __restrict__ T,
                                                const int* __restrict__ offs,
                                                const int2* __restrict__ ep,
                                                const float* __restrict__ bias,
                                                float* __restrict__ out, int n) {
    int wid = blockIdx.x * 4 + (threadIdx.x >> 6);
    int lane = threadIdx.x & 63;
    if (wid >= n) return;
    int beg = offs[wid];
    int end = offs[wid + 1];

    const uint* Tl = (const uint*)T + lane;   // lane's 2-dim slot within a row
    float a0 = 0.f, a1 = 0.f;

    int4 m0 = *(const int4*)(ep + beg);
    int4 m1 = *(const int4*)(ep + beg + 2);
    int4 m2 = *(const int4*)(ep + beg + 4);
    int4 m3 = *(const int4*)(ep + beg + 6);
    int e = beg;
    for (;;) {
        // gather rows for current 8 edges (metadata already in registers)
        uint r0 = Tl[(size_t)m0.x * 64];
        uint r1 = Tl[(size_t)m0.z * 64];
        uint r2 = Tl[(size_t)m1.x * 64];
        uint r3 = Tl[(size_t)m1.z * 64];
        uint r4 = Tl[(size_t)m2.x * 64];
        uint r5 = Tl[(size_t)m2.z * 64];
        uint r6 = Tl[(size_t)m3.x * 64];
        uint r7 = Tl[(size_t)m3.z * 64];
        float w0 = __int_as_float(m0.y), w1 = __int_as_float(m0.w);
        float w2 = __int_as_float(m1.y), w3 = __int_as_float(m1.w);
        float w4 = __int_as_float(m2.y), w5 = __int_as_float(m2.w);
        float w6 = __int_as_float(m3.y), w7 = __int_as_float(m3.w);
        e += 8;
        bool more = (e < end);          // wave-uniform
        if (more) {                      // prefetch next metadata under row latency
            m0 = *(const int4*)(ep + e);
            m1 = *(const int4*)(ep + e + 2);
            m2 = *(const int4*)(ep + e + 4);
            m3 = *(const int4*)(ep + e + 6);
        }
        a0 += w0 * bfu_lo(r0); a1 += w0 * bfu_hi(r0);
        a0 += w1 * bfu_lo(r1); a1 += w1 * bfu_hi(r1);
        a0 += w2 * bfu_lo(r2); a1 += w2 * bfu_hi(r2);
        a0 += w3 * bfu_lo(r3); a1 += w3 * bfu_hi(r3);
        a0 += w4 * bfu_lo(r4); a1 += w4 * bfu_hi(r4);
        a0 += w5 * bfu_lo(r5); a1 += w5 * bfu_hi(r5);
        a0 += w6 * bfu_lo(r6); a1 += w6 * bfu_hi(r6);
        a0 += w7 * bfu_lo(r7); a1 += w7 * bfu_hi(r7);
        if (!more) break;
    }

    float2 b = *(const float2*)(bias + (lane << 1));
    a0 += b.x; a1 += b.y;
    if (RELU) { a0 = fmaxf(a0, 0.f); a1 = fmaxf(a1, 0.f); }
    *(float2*)(out + (size_t)wid * 128 + (lane << 1)) = make_float2(a0, a1);
}

__global__ __launch_bounds__(256) void k_agg64(const __hip_bfloat16* __restrict__ T,
                                               const int* __restrict__ offs,
                                               const int2* __restrict__ ep,
                                               const float* __restrict__ bias,
                                               float* __restrict__ out, int n) {
    int wid = blockIdx.x * 4 + (threadIdx.x >> 6);
    int lane = threadIdx.x & 63;
    if (wid >= n) return;
    int beg = offs[wid];
    int end = offs[wid + 1];

    const ushort* Tl = (const ushort*)T + lane;
    float a0 = 0.f;

    int4 m0 = *(const int4*)(ep + beg);
    int4 m1 = *(const int4*)(ep + beg + 2);
    int4 m2 = *(const int4*)(ep + beg + 4);
    int4 m3 = *(const int4*)(ep + beg + 6);
    int e = beg;
    for (;;) {
        float r0 = __uint_as_float((uint)Tl[(size_t)m0.x * 64] << 16);
        float r1 = __uint_as_float((uint)Tl[(size_t)m0.z * 64] << 16);
        float r2 = __uint_as_float((uint)Tl[(size_t)m1.x * 64] << 16);
        float r3 = __uint_as_float((uint)Tl[(size_t)m1.z * 64] << 16);
        float r4 = __uint_as_float((uint)Tl[(size_t)m2.x * 64] << 16);
        float r5 = __uint_as_float((uint)Tl[(size_t)m2.z * 64] << 16);
        float r6 = __uint_as_float((uint)Tl[(size_t)m3.x * 64] << 16);
        float r7 = __uint_as_float((uint)Tl[(size_t)m3.z * 64] << 16);
        float w0 = __int_as_float(m0.y), w1 = __int_as_float(m0.w);
        float w2 = __int_as_float(m1.y), w3 = __int_as_float(m1.w);
        float w4 = __int_as_float(m2.y), w5 = __int_as_float(m2.w);
        float w6 = __int_as_float(m3.y), w7 = __int_as_float(m3.w);
        e += 8;
        bool more = (e < end);
        if (more) {
            m0 = *(const int4*)(ep + e);
            m1 = *(const int4*)(ep + e + 2);
            m2 = *(const int4*)(ep + e + 4);
            m3 = *(const int4*)(ep + e + 6);
        }
        a0 += w0 * r0 + w1 * r1 + w2 * r2 + w3 * r3;
        a0 += w4 * r4 + w5 * r5 + w6 * r6 + w7 * r7;
        if (!more) break;
    }

    a0 += bias[lane];
    out[(size_t)wid * 64 + lane] = a0;
}

// ---------------------------------------------------------------------------

extern "C" void kernel_launch(void* const* d_in, const int* in_sizes, int n_in,
                              void* d_out, int out_size, void* d_ws, size_t ws_size,
                              hipStream_t stream) {
    const int n = in_sizes[0] / 128;   // 50000
    const int E = in_sizes[1] / 2;     // 800000

    const float* x  = (const float*)d_in[0];
    const int*   ei = (const int*)d_in[1];
    const float* W1 = (const float*)d_in[2];
    const float* b1 = (const float*)d_in[3];
    const float* W2 = (const float*)d_in[4];
    const float* b2 = (const float*)d_in[5];
    const float* W3 = (const float*)d_in[6];
    const float* b3 = (const float*)d_in[7];
    const int* src = ei;        // edge_index[0]
    const int* dst = ei + E;    // edge_index[1]
    float* out = (float*)d_out;

    const int cap = E + 8 * n;  // max padded edge slots (sum of (deg+7)&~7)

    // workspace carve-up (256B aligned)
    char* w = (char*)d_ws;
    auto alloc = [&](size_t bytes) {
        char* p = w;
        w += (bytes + 255) & ~(size_t)255;
        return p;
    };
    int*   deg    = (int*)alloc((size_t)n * 4);
    int*   cursor = (int*)alloc((size_t)n * 4);
    int*   offs   = (int*)alloc((size_t)(n + 1) * 4);
    int*   bsum   = (int*)alloc(256 * 4);
    float* dinv   = (float*)alloc((size_t)n * 4);
    int2*  ep     = (int2*)alloc((size_t)cap * 8);
    __hip_bfloat16* tA = (__hip_bfloat16*)alloc((size_t)n * 128 * 2);  // gathered (bf16)
    float* hB     = (float*)alloc((size_t)n * 128 * 4);                // fp32 activations

    const int nb = (n + 255) / 256;  // 196 (<=256, fits single-block scan)

    // ---- CSR build (degree/norm shared by all 3 layers) ----
    k_init<<<(cap + 255) / 256, 256, 0, stream>>>(deg, n, ep, cap);
    k_hist<<<(E + 255) / 256, 256, 0, stream>>>(dst, E, deg);
    k_scan_block<<<nb, 256, 0, stream>>>(deg, offs, bsum, dinv, n);
    k_scan_bsum<<<1, 256, 0, stream>>>(bsum, nb, offs, n);
    k_add_bsum<<<nb, 256, 0, stream>>>(offs, bsum, cursor, n);
    k_fill<<<(E + n + 255) / 256, 256, 0, stream>>>(src, dst, E, n, cursor, dinv, ep);

    // ---- 3 GCN layers ----
    const int agg_blocks = (n + 3) / 4;     // one wave per node, 4 waves/block
    const int gemm_blocks = (n + 63) / 64;

    k_gemm<128><<<gemm_blocks, 256, 0, stream>>>(x, W1, tA, n);
    k_agg128<true><<<agg_blocks, 256, 0, stream>>>(tA, offs, ep, b1, hB, n);

    k_gemm<128><<<gemm_blocks, 256, 0, stream>>>(hB, W2, tA, n);
    k_agg128<true><<<agg_blocks, 256, 0, stream>>>(tA, offs, ep, b2, hB, n);

    k_gemm<64><<<gemm_blocks, 256, 0, stream>>>(hB, W3, tA, n);
    k_agg64<<<agg_blocks, 256, 0, stream>>>(tA, offs, ep, b3, out, n);
}